// Round 8
// baseline (143.627 us; speedup 1.0000x reference)
//
#include <hip/hip_runtime.h>

#define BB 4
#define NN 4
#define TT 4
#define AA 128
#define DD 64
#define HWD 36864              // 192*192
#define NPTS (BB * NN * HWD)   // 589824
#define NG (BB * TT * AA)      // 2048
#define SL 128                 // slabs per image
#define SPTS (HWD / SL)        // 288 points per slab
#define NBLK (BB * TT * SL)    // 2048 blocks

__device__ __constant__ int c_ti[4] = {0, 0, 0, 1};
__device__ __constant__ int c_tj[4] = {1, 1, 2, 2};
__device__ __constant__ int c_tk[4] = {2, 3, 3, 3};

// ---------------------------------------------------------------------------
// K0: pack pointmaps into float4 (x, y, z, |p|^2).  (R2 verbatim — proven.)
// ---------------------------------------------------------------------------
__global__ __launch_bounds__(256) void
pack_kernel(const float* __restrict__ pts, float4* __restrict__ pk4) {
#pragma clang fp contract(off)
    const int idx = blockIdx.x * 256 + threadIdx.x;
    if (idx < NPTS) {
        const float x = pts[idx * 3 + 0];
        const float y = pts[idx * 3 + 1];
        const float z = pts[idx * 3 + 2];
        pk4[idx] = make_float4(x, y, z, x * x + y * y + z * z);
    }
}

// ---------------------------------------------------------------------------
// K1: scan1 (R2 body verbatim). Block = (bt, slab), 128 threads = 128 anchor
// queries. The whole wave reads the SAME packed point each step (uniform
// address -> scalar-cache broadcast). Key = s2 - 2*dot (order-equivalent to
// d2; per-query |q|^2 added at combine time).
// ---------------------------------------------------------------------------
__global__ __launch_bounds__(128) void
scan1_kernel(const float4* __restrict__ pk4,
             const int* __restrict__ anchor_idx,
             float* __restrict__ pkey1,
             int* __restrict__ pidx1) {
    const int slab = blockIdx.x & (SL - 1);
    const int bt = blockIdx.x >> 7;
    const int t = bt & 3;
    const int b = bt >> 2;
    const int g = bt * AA + threadIdx.x;

    const int qpix = anchor_idx[g];
    const float4 q = pk4[(b * NN + c_ti[t]) * HWD + qpix];
    const float m2x = -2.0f * q.x;
    const float m2y = -2.0f * q.y;
    const float m2z = -2.0f * q.z;

    const float4* sp = pk4 + (b * NN + c_tj[t]) * HWD + slab * SPTS;

    float best = 3.4e38f;
    int besti = 0;
#pragma unroll 4
    for (int p = 0; p < SPTS; ++p) {
        const float4 P = sp[p];
        const float key = fmaf(P.x, m2x, fmaf(P.y, m2y, fmaf(P.z, m2z, P.w)));
        if (key < best) { best = key; besti = p; }   // ascending -> first occ
    }
    pkey1[slab * NG + g] = best;
    pidx1[slab * NG + g] = slab * SPTS + besti;
}

// ---------------------------------------------------------------------------
// K2: combine1 (key-only, coalesced [slab][g] reads; winner slab's idx
// fetched once; first-min-slab => first occurrence — proven R4/R7) fused with
// scan2 (R2-style uniform stream of image tk; query = pts_j[idx_j]).
// slab==0 blocks publish min_ij / idx_j.  Block 0 zeroes K3's counter.
// ---------------------------------------------------------------------------
__global__ __launch_bounds__(128) void
scan2_kernel(const float4* __restrict__ pk4,
             const int* __restrict__ anchor_idx,
             const float* __restrict__ pkey1,
             const int* __restrict__ pidx1,
             float* __restrict__ min_ij,
             int* __restrict__ idx_j_out,
             float* __restrict__ pkey2,
             int* __restrict__ pidx2,
             int* __restrict__ ctr) {
#pragma clang fp contract(off)
    const int tid = threadIdx.x;
    const int slab = blockIdx.x & (SL - 1);
    const int bt = blockIdx.x >> 7;
    const int t = bt & 3;
    const int b = bt >> 2;
    const int g = bt * AA + tid;

    if (blockIdx.x == 0 && tid == 0) ctr[0] = 0;

    // combine1: key-only slab scan, then a single idx fetch for the winner
    float bk = 3.4e38f;
    int s0 = 0;
#pragma unroll 4
    for (int c = 0; c < SL; ++c) {
        const float k = pkey1[c * NG + g];
        if (k < bk) { bk = k; s0 = c; }   // ascending c -> first occurrence
    }
    const int ij = pidx1[s0 * NG + g];

    if (slab == 0) {
        const float4 q = pk4[(b * NN + c_ti[t]) * HWD + anchor_idx[g]];
        min_ij[g] = sqrtf(fmaxf(bk + q.w, 0.0f));
        idx_j_out[g] = ij;
    }

    // scan2: query = chosen point of image tj
    const float4 jq = pk4[(b * NN + c_tj[t]) * HWD + ij];
    const float m2x = -2.0f * jq.x;
    const float m2y = -2.0f * jq.y;
    const float m2z = -2.0f * jq.z;

    const float4* sp = pk4 + (b * NN + c_tk[t]) * HWD + slab * SPTS;

    float best = 3.4e38f;
    int besti = 0;
#pragma unroll 4
    for (int p = 0; p < SPTS; ++p) {
        const float4 P = sp[p];
        const float key = fmaf(P.x, m2x, fmaf(P.y, m2y, fmaf(P.z, m2z, P.w)));
        if (key < best) { best = key; besti = p; }
    }
    pkey2[slab * NG + g] = best;
    pidx2[slab * NG + g] = slab * SPTS + besti;
}

// ---------------------------------------------------------------------------
// K3: 16 blocks (one per bt), 128 threads (one per anchor). Verbatim from
// rounds 5/7 (passed): combine2 -> min_jk/idx_k; dki vs LDS-staged anchors;
// feature SE; block reduce; finish-counter; last block -> scalar.
// ---------------------------------------------------------------------------
__global__ __launch_bounds__(128) void
pass3_kernel(const float* __restrict__ pts,
             const float* __restrict__ feats,
             const int* __restrict__ anchor_idx,
             const float* __restrict__ min_ij,
             const int* __restrict__ idx_j_in,
             const float* __restrict__ pkey2,
             const int* __restrict__ pidx2,
             float* __restrict__ loss_bt,
             float* __restrict__ batch_ok,
             int* __restrict__ ctr,
             float* __restrict__ out) {
#pragma clang fp contract(off)
    const int bt = blockIdx.x;
    const int t = bt & 3;
    const int b = bt >> 2;
    const int i = c_ti[t];
    const int k = c_tk[t];
    const int tid = threadIdx.x;
    const int g = bt * AA + tid;

    // combine2
    float bkey = 3.4e38f;
    int ik = 0;
    for (int c = 0; c < SL; ++c) {
        const float kk = pkey2[c * NG + g];
        const int ii = pidx2[c * NG + g];
        if (kk < bkey) { bkey = kk; ik = ii; }
    }
    const int qpj = idx_j_in[g];
    const float* jp = pts + ((long)(b * NN + c_tj[t]) * HWD + qpj) * 3;
    const float jx = jp[0], jy = jp[1], jz = jp[2];
    const float min_jk =
        sqrtf(fmaxf(bkey + (jx * jx + jy * jy + jz * jz), 0.0f));

    // dki
    const int ai = anchor_idx[g];
    const float* ap = pts + ((long)(b * NN + i) * HWD + ai) * 3;
    __shared__ float aps[AA][3];
    aps[tid][0] = ap[0];
    aps[tid][1] = ap[1];
    aps[tid][2] = ap[2];
    const float* kp = pts + ((long)(b * NN + k) * HWD + ik) * 3;
    const float kx = kp[0], ky = kp[1], kz = kp[2];
    const float sk = kx * kx + ky * ky + kz * kz;
    __syncthreads();

    float best = 3.4e38f;
    int besti = 0;
    for (int a2 = 0; a2 < AA; ++a2) {
        const float qx = aps[a2][0], qy = aps[a2][1], qz = aps[a2][2];
        const float s2 = qx * qx + qy * qy + qz * qz;
        const float dot = kx * qx + ky * qy + kz * qz;
        const float d2 = (sk + s2) - 2.0f * dot;
        if (d2 < best) { best = d2; besti = a2; }
    }
    const float min_ki = sqrtf(fmaxf(best, 0.0f));

    const int valid =
        (min_ij[g] < 0.3f) && (min_jk < 0.3f) && (min_ki < 0.3f);

    // feat_ret: reference quirk — raw pixel index besti in [0,128)
    const float* fr = feats + ((long)(b * NN + i) * HWD + besti) * DD;
    const float* fa = feats + ((long)(b * NN + i) * HWD + ai) * DD;
    float snr = 0.0f, sna = 0.0f;
    for (int d = 0; d < DD; ++d) { const float x = fr[d]; snr += x * x; }
    for (int d = 0; d < DD; ++d) { const float y = fa[d]; sna += y * y; }
    const float nr = fmaxf(sqrtf(snr), 1e-12f);
    const float na = fmaxf(sqrtf(sna), 1e-12f);
    float se = 0.0f;
    for (int d = 0; d < DD; ++d) {
        const float x = fr[d] / nr - fa[d] / na;
        se += x * x;
    }

    __shared__ float sred[2][AA];
    sred[0][tid] = (float)valid;
    sred[1][tid] = valid ? se : 0.0f;
    __syncthreads();
    for (int s = 64; s > 0; s >>= 1) {
        if (tid < s) {
            sred[0][tid] += sred[0][tid + s];
            sred[1][tid] += sred[1][tid + s];
        }
        __syncthreads();
    }
    if (tid == 0) {
        const float cnt = sred[0][0];
        const float lbt = (cnt > 0.0f)
                              ? sred[1][0] / (fmaxf(cnt, 1.0f) * (float)DD)
                              : 0.0f;
        const float ok = (cnt >= 5.0f) ? 1.0f : 0.0f;
        atomicExch(&loss_bt[bt], lbt);     // device-scope write-through
        atomicExch(&batch_ok[bt], ok);
        __threadfence();                   // only 16 blocks — amortized
        const int old = atomicAdd(ctr, 1);
        if (old == 15) {
            float s = 0.0f;
            for (int tt = 0; tt < TT; ++tt) {
                float tc = 0.0f, sl = 0.0f;
                for (int bb = 0; bb < BB; ++bb) {
                    const float okv = atomicAdd(&batch_ok[bb * TT + tt], 0.0f);
                    const float lv = atomicAdd(&loss_bt[bb * TT + tt], 0.0f);
                    tc += okv;
                    sl += lv * okv;
                }
                s += (tc > 0.0f) ? sl / fmaxf(tc, 1.0f) : 0.0f;
            }
            out[0] = s / (float)TT;
        }
    }
}

extern "C" void kernel_launch(void* const* d_in, const int* in_sizes, int n_in,
                              void* d_out, int out_size, void* d_ws,
                              size_t ws_size, hipStream_t stream) {
    const float* feats = (const float*)d_in[0];   // (B,N,H,W,D) f32
    const float* pts = (const float*)d_in[1];     // (B,N,H,W,3) f32
    const int* anchor = (const int*)d_in[2];      // (B,T,A) i32
    float* out = (float*)d_out;

    float* ws = (float*)d_ws;
    float4* pk4 = (float4*)ws;                       // NPTS float4 (9.4 MB)
    float* pkey1 = ws + NPTS * 4;                    // SL*NG f32 (1 MB)
    int* pidx1 = (int*)(pkey1 + SL * NG);
    float* pkey2 = pkey1 + 2 * SL * NG;
    int* pidx2 = (int*)(pkey1 + 3 * SL * NG);
    float* min_ij = pkey1 + 4 * SL * NG;             // NG
    int* idx_j = (int*)(min_ij + NG);                // NG
    float* loss_bt = min_ij + 2 * NG;                // 16
    float* batch_ok = loss_bt + 16;                  // 16
    int* ctr = (int*)(batch_ok + 16);                // 1

    pack_kernel<<<(NPTS + 255) / 256, 256, 0, stream>>>(pts, pk4);
    scan1_kernel<<<NBLK, 128, 0, stream>>>(pk4, anchor, pkey1, pidx1);
    scan2_kernel<<<NBLK, 128, 0, stream>>>(pk4, anchor, pkey1, pidx1, min_ij,
                                           idx_j, pkey2, pidx2, ctr);
    pass3_kernel<<<BB * TT, 128, 0, stream>>>(pts, feats, anchor, min_ij,
                                              idx_j, pkey2, pidx2, loss_bt,
                                              batch_ok, ctr, out);
}

// Round 9
// 97.924 us; speedup vs baseline: 1.4667x; 1.4667x over previous
//
#include <hip/hip_runtime.h>

#define BB 4
#define NN 4
#define TT 4
#define AA 128
#define DD 64
#define HWD 36864              // 192*192
#define NPTS (BB * NN * HWD)   // 589824
#define NG (BB * TT * AA)      // 2048
#define CHUNKS 128
#define CPTS (HWD / CHUNKS)    // 288

__device__ __constant__ int c_ti[4] = {0, 0, 0, 1};
__device__ __constant__ int c_tj[4] = {1, 1, 2, 2};
__device__ __constant__ int c_tk[4] = {2, 3, 3, 3};

// Scalar-pipe (SMEM) view of read-only global data: the scan's point stream
// address is wave-uniform, so loads through addrspace(4) compile to
// s_load_dwordx4 on the scalar pipe, bypassing the shared L1 vector port.
typedef const __attribute__((address_space(4))) float cfloat;

// ---------------------------------------------------------------------------
// K0: pack pointmaps into float4 (x, y, z, |p|^2).  (R2 verbatim — proven.)
// ---------------------------------------------------------------------------
__global__ __launch_bounds__(256) void
pack_kernel(const float* __restrict__ pts, float4* __restrict__ pk4) {
#pragma clang fp contract(off)
    const int idx = blockIdx.x * 256 + threadIdx.x;
    if (idx < NPTS) {
        const float x = pts[idx * 3 + 0];
        const float y = pts[idx * 3 + 1];
        const float z = pts[idx * 3 + 2];
        pk4[idx] = make_float4(x, y, z, x * x + y * y + z * z);
    }
}

// ---------------------------------------------------------------------------
// K1/K3: NN scan (R2 structure; block=(bt,chunk), 128 threads = 128 queries).
// Point stream read via the SCALAR pipe (uniform address). Key = s2 - 2*dot.
// PASS 1: query = anchor point of image ti, scan image tj.
// PASS 2: query = pts_j[idx_j],            scan image tk.
// ---------------------------------------------------------------------------
template <int PASS>
__global__ __launch_bounds__(128) void
nn_scan_kernel(const float4* __restrict__ pk4,
               const int* __restrict__ anchor_idx,
               const int* __restrict__ prev_idx,
               float* __restrict__ pkey,
               int* __restrict__ pidx) {
    const int chunk = blockIdx.x & (CHUNKS - 1);
    const int bt = blockIdx.x >> 7;
    const int t = bt & 3;
    const int b = bt >> 2;
    const int g = bt * AA + threadIdx.x;

    int qimg, simg, qpix;
    if (PASS == 1) {
        qimg = c_ti[t];
        simg = c_tj[t];
        qpix = anchor_idx[g];
    } else {
        qimg = c_tj[t];
        simg = c_tk[t];
        qpix = prev_idx[g];
    }

    const float4 q = pk4[(b * NN + qimg) * HWD + qpix];
    const float m2x = -2.0f * q.x;
    const float m2y = -2.0f * q.y;
    const float m2z = -2.0f * q.z;

    const float4* sp = pk4 + (b * NN + simg) * HWD + chunk * CPTS;
    cfloat* sps = (cfloat*)(unsigned long long)sp;   // scalar-pipe stream

    float best = 3.4e38f;
    int besti = 0;
#pragma unroll 8
    for (int p = 0; p < CPTS; ++p) {
        const float x = sps[4 * p + 0];
        const float y = sps[4 * p + 1];
        const float z = sps[4 * p + 2];
        const float w = sps[4 * p + 3];
        const float key = fmaf(x, m2x, fmaf(y, m2y, fmaf(z, m2z, w)));
        if (key < best) { best = key; besti = p; }   // ascending -> first occ
    }
    pkey[chunk * NG + g] = best;
    pidx[chunk * NG + g] = chunk * CPTS + besti;
}

// ---------------------------------------------------------------------------
// K2/K4: combine (R2 verbatim — proven). Block = one g; 128 threads = 128
// chunk partials; LDS tree with smaller-idx tie-break => first occurrence.
// min = sqrt(max(key + |q|^2, 0)).  PASS 2 also zeroes pass3's counter.
// ---------------------------------------------------------------------------
template <int PASS>
__global__ __launch_bounds__(128) void
combine_kernel(const float4* __restrict__ pk4,
               const int* __restrict__ anchor_idx,
               const int* __restrict__ prev_idx,
               const float* __restrict__ pkey,
               const int* __restrict__ pidx,
               float* __restrict__ out_min,
               int* __restrict__ out_idx,
               int* __restrict__ ctr) {
    const int g = blockIdx.x;
    const int c = threadIdx.x;

    if (PASS == 2 && g == 0 && c == 0) ctr[0] = 0;

    __shared__ float sk[128];
    __shared__ int si[128];
    sk[c] = pkey[c * NG + g];
    si[c] = pidx[c * NG + g];
    __syncthreads();
    for (int s = 64; s > 0; s >>= 1) {
        if (c < s) {
            const float ok = sk[c + s];
            const int oi = si[c + s];
            if (ok < sk[c] || (ok == sk[c] && oi < si[c])) {
                sk[c] = ok;
                si[c] = oi;
            }
        }
        __syncthreads();
    }
    if (c == 0) {
        const int t = (g / AA) & 3;
        const int b = g / (AA * TT);
        const int qimg = (PASS == 1) ? c_ti[t] : c_tj[t];
        const int qpix = (PASS == 1) ? anchor_idx[g] : prev_idx[g];
        const float4 q = pk4[(b * NN + qimg) * HWD + qpix];
        out_min[g] = sqrtf(fmaxf(sk[0] + q.w, 0.0f));
        out_idx[g] = si[0];
    }
}

// ---------------------------------------------------------------------------
// K5: pass3 (R2 verbatim) + counter-chained final tail (proven R4/5/7/8).
// 16 blocks, 128 threads (one per anchor).
// ---------------------------------------------------------------------------
__global__ __launch_bounds__(128) void
pass3_kernel(const float* __restrict__ pts,
             const float* __restrict__ feats,
             const int* __restrict__ anchor_idx,
             const float* __restrict__ min_ij,
             const float* __restrict__ min_jk,
             const int* __restrict__ idx_k,
             float* __restrict__ loss_bt,
             float* __restrict__ batch_ok,
             int* __restrict__ ctr,
             float* __restrict__ out) {
#pragma clang fp contract(off)
    const int bt = blockIdx.x;
    const int t = bt & 3;
    const int b = bt >> 2;
    const int i = c_ti[t];
    const int k = c_tk[t];
    const int tid = threadIdx.x;
    const int g = bt * AA + tid;

    const int ai = anchor_idx[g];
    const float* ap = pts + ((long)(b * NN + i) * HWD + ai) * 3;

    __shared__ float aps[AA][3];
    aps[tid][0] = ap[0];
    aps[tid][1] = ap[1];
    aps[tid][2] = ap[2];

    const int ik = idx_k[g];
    const float* kp = pts + ((long)(b * NN + k) * HWD + ik) * 3;
    const float kx = kp[0], ky = kp[1], kz = kp[2];
    const float sk = kx * kx + ky * ky + kz * kz;
    __syncthreads();

    float best = 3.4e38f;
    int besti = 0;
    for (int a2 = 0; a2 < AA; ++a2) {
        const float qx = aps[a2][0], qy = aps[a2][1], qz = aps[a2][2];
        const float s2 = qx * qx + qy * qy + qz * qz;
        const float dot = kx * qx + ky * qy + kz * qz;
        const float d2 = (sk + s2) - 2.0f * dot;
        if (d2 < best) { best = d2; besti = a2; }
    }
    const float min_ki = sqrtf(fmaxf(best, 0.0f));

    const int valid =
        (min_ij[g] < 0.3f) && (min_jk[g] < 0.3f) && (min_ki < 0.3f);

    // feat_ret: reference quirk — raw pixel index besti in [0,128)
    const float* fr = feats + ((long)(b * NN + i) * HWD + besti) * DD;
    const float* fa = feats + ((long)(b * NN + i) * HWD + ai) * DD;
    float snr = 0.0f, sna = 0.0f;
    for (int d = 0; d < DD; ++d) { const float x = fr[d]; snr += x * x; }
    for (int d = 0; d < DD; ++d) { const float y = fa[d]; sna += y * y; }
    const float nr = fmaxf(sqrtf(snr), 1e-12f);
    const float na = fmaxf(sqrtf(sna), 1e-12f);
    float se = 0.0f;
    for (int d = 0; d < DD; ++d) {
        const float x = fr[d] / nr - fa[d] / na;
        se += x * x;
    }

    __shared__ float sred[2][AA];
    sred[0][tid] = (float)valid;
    sred[1][tid] = valid ? se : 0.0f;
    __syncthreads();
    for (int s = 64; s > 0; s >>= 1) {
        if (tid < s) {
            sred[0][tid] += sred[0][tid + s];
            sred[1][tid] += sred[1][tid + s];
        }
        __syncthreads();
    }
    if (tid == 0) {
        const float cnt = sred[0][0];
        const float lbt = (cnt > 0.0f)
                              ? sred[1][0] / (fmaxf(cnt, 1.0f) * (float)DD)
                              : 0.0f;
        const float ok = (cnt >= 5.0f) ? 1.0f : 0.0f;
        atomicExch(&loss_bt[bt], lbt);     // device-scope write-through
        atomicExch(&batch_ok[bt], ok);
        __threadfence();                   // only 16 blocks — amortized
        const int old = atomicAdd(ctr, 1);
        if (old == 15) {
            float s = 0.0f;
            for (int tt = 0; tt < TT; ++tt) {
                float tc = 0.0f, sl = 0.0f;
                for (int bb = 0; bb < BB; ++bb) {
                    const float okv = atomicAdd(&batch_ok[bb * TT + tt], 0.0f);
                    const float lv = atomicAdd(&loss_bt[bb * TT + tt], 0.0f);
                    tc += okv;
                    sl += lv * okv;
                }
                s += (tc > 0.0f) ? sl / fmaxf(tc, 1.0f) : 0.0f;
            }
            out[0] = s / (float)TT;
        }
    }
}

extern "C" void kernel_launch(void* const* d_in, const int* in_sizes, int n_in,
                              void* d_out, int out_size, void* d_ws,
                              size_t ws_size, hipStream_t stream) {
    const float* feats = (const float*)d_in[0];   // (B,N,H,W,D) f32
    const float* pts = (const float*)d_in[1];     // (B,N,H,W,3) f32
    const int* anchor = (const int*)d_in[2];      // (B,T,A) i32
    float* out = (float*)d_out;

    float* ws = (float*)d_ws;
    float4* pk4 = (float4*)ws;                       // NPTS float4 (9.4 MB)
    float* pkey1 = ws + NPTS * 4;                    // CHUNKS*NG f32 (1 MB)
    int* pidx1 = (int*)(pkey1 + CHUNKS * NG);
    float* pkey2 = pkey1 + 2 * CHUNKS * NG;
    int* pidx2 = (int*)(pkey1 + 3 * CHUNKS * NG);
    float* min_ij = pkey1 + 4 * CHUNKS * NG;         // NG
    int* idx_j = (int*)(min_ij + NG);                // NG
    float* min_jk = min_ij + 2 * NG;                 // NG
    int* idx_k = (int*)(min_ij + 3 * NG);            // NG
    float* loss_bt = min_ij + 4 * NG;                // 16
    float* batch_ok = loss_bt + 16;                  // 16
    int* ctr = (int*)(batch_ok + 16);                // 1

    pack_kernel<<<(NPTS + 255) / 256, 256, 0, stream>>>(pts, pk4);

    nn_scan_kernel<1><<<BB * TT * CHUNKS, 128, 0, stream>>>(pk4, anchor,
                                                            nullptr, pkey1,
                                                            pidx1);
    combine_kernel<1><<<NG, 128, 0, stream>>>(pk4, anchor, nullptr, pkey1,
                                              pidx1, min_ij, idx_j, ctr);

    nn_scan_kernel<2><<<BB * TT * CHUNKS, 128, 0, stream>>>(pk4, anchor, idx_j,
                                                            pkey2, pidx2);
    combine_kernel<2><<<NG, 128, 0, stream>>>(pk4, anchor, idx_j, pkey2, pidx2,
                                              min_jk, idx_k, ctr);

    pass3_kernel<<<BB * TT, 128, 0, stream>>>(pts, feats, anchor, min_ij,
                                              min_jk, idx_k, loss_bt, batch_ok,
                                              ctr, out);
}

// Round 10
// 84.970 us; speedup vs baseline: 1.6903x; 1.1525x over previous
//
#include <hip/hip_runtime.h>

#define BB 4
#define NN 4
#define TT 4
#define AA 128
#define DD 64
#define HWD 36864              // 192*192
#define NG (BB * TT * AA)      // 2048
#define CHUNKS 128
#define CPTS (HWD / CHUNKS)    // 288
#define NBLK (BB * TT * CHUNKS)  // 2048

__device__ __constant__ int c_ti[4] = {0, 0, 0, 1};
__device__ __constant__ int c_tj[4] = {1, 1, 2, 2};
__device__ __constant__ int c_tk[4] = {2, 3, 3, 3};

// Scalar-pipe (SMEM) view of read-only global data (wave-uniform addresses).
typedef const __attribute__((address_space(4))) float cfloat;

// Order-monotone float<->uint mapping: f1 < f2  <=>  fmap(f1) < fmap(f2).
__device__ __forceinline__ unsigned int fmap(float f) {
    const unsigned int b = __float_as_uint(f);
    return (b & 0x80000000u) ? ~b : (b | 0x80000000u);
}
__device__ __forceinline__ float funmap(unsigned int m) {
    const unsigned int b = (m & 0x80000000u) ? (m ^ 0x80000000u) : ~m;
    return __uint_as_float(b);
}

// ---------------------------------------------------------------------------
// K1: scan1. Block=(bt,chunk), 128 threads = 128 anchor queries. Streams raw
// pts of image tj via the scalar pipe; s2 computed inline (contract off —
// bit-identical to the old pack kernel). Partial published via u64 atomicMin:
//   val = (fmap(key) << 32) | global_point_idx
// -> min key with smaller-index tie-break == numpy first-occurrence argmin.
// Slots pre-armed to 0xFFFF... (= +inf) by a memset node each call.
// ---------------------------------------------------------------------------
__global__ __launch_bounds__(128) void
scan1_kernel(const float* __restrict__ pts,
             const int* __restrict__ anchor_idx,
             unsigned long long* __restrict__ slot1) {
#pragma clang fp contract(off)
    const int chunk = blockIdx.x & (CHUNKS - 1);
    const int bt = blockIdx.x >> 7;
    const int t = bt & 3;
    const int b = bt >> 2;
    const int g = bt * AA + threadIdx.x;

    const int qpix = anchor_idx[g];
    const float* qp = pts + ((long)(b * NN + c_ti[t]) * HWD + qpix) * 3;
    const float m2x = -2.0f * qp[0];
    const float m2y = -2.0f * qp[1];
    const float m2z = -2.0f * qp[2];

    const float* sp =
        pts + ((long)(b * NN + c_tj[t]) * HWD + chunk * CPTS) * 3;
    cfloat* sps = (cfloat*)(unsigned long long)sp;   // scalar-pipe stream

    float best = 3.4e38f;
    int besti = 0;
#pragma unroll 8
    for (int p = 0; p < CPTS; ++p) {
        const float x = sps[3 * p + 0];
        const float y = sps[3 * p + 1];
        const float z = sps[3 * p + 2];
        const float s2 = x * x + y * y + z * z;       // == old pack (contract off)
        const float key = fmaf(x, m2x, fmaf(y, m2y, fmaf(z, m2z, s2)));
        if (key < best) { best = key; besti = p; }    // ascending -> first occ
    }
    const unsigned long long v =
        ((unsigned long long)fmap(best) << 32) |
        (unsigned int)(chunk * CPTS + besti);
    atomicMin(&slot1[g], v);
}

// ---------------------------------------------------------------------------
// K2: scan2. idx_j comes straight from slot1[g] (low 32 bits). Streams image
// tk the same way; publishes into slot2 via atomicMin. Block 0 zeroes K3's
// finish counter.
// ---------------------------------------------------------------------------
__global__ __launch_bounds__(128) void
scan2_kernel(const float* __restrict__ pts,
             const unsigned long long* __restrict__ slot1,
             unsigned long long* __restrict__ slot2,
             int* __restrict__ ctr) {
#pragma clang fp contract(off)
    const int tid = threadIdx.x;
    const int chunk = blockIdx.x & (CHUNKS - 1);
    const int bt = blockIdx.x >> 7;
    const int t = bt & 3;
    const int b = bt >> 2;
    const int g = bt * AA + tid;

    if (blockIdx.x == 0 && tid == 0) ctr[0] = 0;

    const int ij = (int)(slot1[g] & 0xFFFFFFFFull);
    const float* jp = pts + ((long)(b * NN + c_tj[t]) * HWD + ij) * 3;
    const float m2x = -2.0f * jp[0];
    const float m2y = -2.0f * jp[1];
    const float m2z = -2.0f * jp[2];

    const float* sp =
        pts + ((long)(b * NN + c_tk[t]) * HWD + chunk * CPTS) * 3;
    cfloat* sps = (cfloat*)(unsigned long long)sp;

    float best = 3.4e38f;
    int besti = 0;
#pragma unroll 8
    for (int p = 0; p < CPTS; ++p) {
        const float x = sps[3 * p + 0];
        const float y = sps[3 * p + 1];
        const float z = sps[3 * p + 2];
        const float s2 = x * x + y * y + z * z;
        const float key = fmaf(x, m2x, fmaf(y, m2y, fmaf(z, m2z, s2)));
        if (key < best) { best = key; besti = p; }
    }
    const unsigned long long v =
        ((unsigned long long)fmap(best) << 32) |
        (unsigned int)(chunk * CPTS + besti);
    atomicMin(&slot2[g], v);
}

// ---------------------------------------------------------------------------
// K3: pass3 + chained final (16 blocks, 128 threads). min_ij/min_jk/idx_k
// reconstructed from the slots; dki vs LDS-staged anchors; feature SE; block
// reduce; finish-counter; last block -> scalar.  (Body proven R4-R9.)
// ---------------------------------------------------------------------------
__global__ __launch_bounds__(128) void
pass3_kernel(const float* __restrict__ pts,
             const float* __restrict__ feats,
             const int* __restrict__ anchor_idx,
             const unsigned long long* __restrict__ slot1,
             const unsigned long long* __restrict__ slot2,
             float* __restrict__ loss_bt,
             float* __restrict__ batch_ok,
             int* __restrict__ ctr,
             float* __restrict__ out) {
#pragma clang fp contract(off)
    const int bt = blockIdx.x;
    const int t = bt & 3;
    const int b = bt >> 2;
    const int i = c_ti[t];
    const int k = c_tk[t];
    const int tid = threadIdx.x;
    const int g = bt * AA + tid;

    // anchor point & |q|^2
    const int ai = anchor_idx[g];
    const float* ap = pts + ((long)(b * NN + i) * HWD + ai) * 3;
    const float ax = ap[0], ay = ap[1], az = ap[2];
    const float sq = ax * ax + ay * ay + az * az;

    // min_ij from slot1
    const unsigned long long s1 = slot1[g];
    const float key1 = funmap((unsigned int)(s1 >> 32));
    const float min_ij = sqrtf(fmaxf(key1 + sq, 0.0f));
    const int ij = (int)(s1 & 0xFFFFFFFFull);

    // min_jk from slot2 (needs |pj|^2)
    const float* jp = pts + ((long)(b * NN + c_tj[t]) * HWD + ij) * 3;
    const float jx = jp[0], jy = jp[1], jz = jp[2];
    const float sqj = jx * jx + jy * jy + jz * jz;
    const unsigned long long s2v = slot2[g];
    const float key2 = funmap((unsigned int)(s2v >> 32));
    const float min_jk = sqrtf(fmaxf(key2 + sqj, 0.0f));
    const int ik = (int)(s2v & 0xFFFFFFFFull);

    // dki
    __shared__ float aps[AA][3];
    aps[tid][0] = ax;
    aps[tid][1] = ay;
    aps[tid][2] = az;
    const float* kp = pts + ((long)(b * NN + k) * HWD + ik) * 3;
    const float kx = kp[0], ky = kp[1], kz = kp[2];
    const float sk = kx * kx + ky * ky + kz * kz;
    __syncthreads();

    float best = 3.4e38f;
    int besti = 0;
    for (int a2 = 0; a2 < AA; ++a2) {
        const float qx = aps[a2][0], qy = aps[a2][1], qz = aps[a2][2];
        const float s2 = qx * qx + qy * qy + qz * qz;
        const float dot = kx * qx + ky * qy + kz * qz;
        const float d2 = (sk + s2) - 2.0f * dot;
        if (d2 < best) { best = d2; besti = a2; }
    }
    const float min_ki = sqrtf(fmaxf(best, 0.0f));

    const int valid =
        (min_ij < 0.3f) && (min_jk < 0.3f) && (min_ki < 0.3f);

    // feat_ret: reference quirk — raw pixel index besti in [0,128)
    const float* fr = feats + ((long)(b * NN + i) * HWD + besti) * DD;
    const float* fa = feats + ((long)(b * NN + i) * HWD + ai) * DD;
    float snr = 0.0f, sna = 0.0f;
    for (int d = 0; d < DD; ++d) { const float x = fr[d]; snr += x * x; }
    for (int d = 0; d < DD; ++d) { const float y = fa[d]; sna += y * y; }
    const float nr = fmaxf(sqrtf(snr), 1e-12f);
    const float na = fmaxf(sqrtf(sna), 1e-12f);
    float se = 0.0f;
    for (int d = 0; d < DD; ++d) {
        const float x = fr[d] / nr - fa[d] / na;
        se += x * x;
    }

    __shared__ float sred[2][AA];
    sred[0][tid] = (float)valid;
    sred[1][tid] = valid ? se : 0.0f;
    __syncthreads();
    for (int s = 64; s > 0; s >>= 1) {
        if (tid < s) {
            sred[0][tid] += sred[0][tid + s];
            sred[1][tid] += sred[1][tid + s];
        }
        __syncthreads();
    }
    if (tid == 0) {
        const float cnt = sred[0][0];
        const float lbt = (cnt > 0.0f)
                              ? sred[1][0] / (fmaxf(cnt, 1.0f) * (float)DD)
                              : 0.0f;
        const float ok = (cnt >= 5.0f) ? 1.0f : 0.0f;
        atomicExch(&loss_bt[bt], lbt);     // device-scope write-through
        atomicExch(&batch_ok[bt], ok);
        __threadfence();                   // only 16 blocks — amortized
        const int old = atomicAdd(ctr, 1);
        if (old == 15) {
            float s = 0.0f;
            for (int tt = 0; tt < TT; ++tt) {
                float tc = 0.0f, sl = 0.0f;
                for (int bb = 0; bb < BB; ++bb) {
                    const float okv = atomicAdd(&batch_ok[bb * TT + tt], 0.0f);
                    const float lv = atomicAdd(&loss_bt[bb * TT + tt], 0.0f);
                    tc += okv;
                    sl += lv * okv;
                }
                s += (tc > 0.0f) ? sl / fmaxf(tc, 1.0f) : 0.0f;
            }
            out[0] = s / (float)TT;
        }
    }
}

extern "C" void kernel_launch(void* const* d_in, const int* in_sizes, int n_in,
                              void* d_out, int out_size, void* d_ws,
                              size_t ws_size, hipStream_t stream) {
    const float* feats = (const float*)d_in[0];   // (B,N,H,W,D) f32
    const float* pts = (const float*)d_in[1];     // (B,N,H,W,3) f32
    const int* anchor = (const int*)d_in[2];      // (B,T,A) i32
    float* out = (float*)d_out;

    unsigned long long* slot1 = (unsigned long long*)d_ws;   // NG u64
    unsigned long long* slot2 = slot1 + NG;                  // NG u64
    float* loss_bt = (float*)(slot2 + NG);                   // 16
    float* batch_ok = loss_bt + 16;                          // 16
    int* ctr = (int*)(batch_ok + 16);                        // 1

    // Arm both slot arrays to +inf sentinel (0xFF... = max u64) every call.
    hipMemsetAsync(slot1, 0xFF, 2 * NG * sizeof(unsigned long long), stream);

    scan1_kernel<<<NBLK, 128, 0, stream>>>(pts, anchor, slot1);
    scan2_kernel<<<NBLK, 128, 0, stream>>>(pts, slot1, slot2, ctr);
    pass3_kernel<<<BB * TT, 128, 0, stream>>>(pts, feats, anchor, slot1,
                                              slot2, loss_bt, batch_ok, ctr,
                                              out);
}